// Round 2
// baseline (636.753 us; speedup 1.0000x reference)
//
#include <hip/hip_runtime.h>
#include <hip/hip_bf16.h>
#include <hip/hip_fp16.h>

// Self-attention, N=8192 tokens, H=1024, fp32 in/out.
// All GEMMs via fp16 MFMA (mfma_f32_16x16x32_f16, fp32 accumulate) in BT form
// A[M][K] * B[N][K]^T:
//   1. x -> fp16
//   2. Wq/Wk/Wv -> fp16 transposed
//   3. q,k,v = x@W + b   (fp16; v transposed afterwards for PV GEMM)
//   4. S = q@k^T         (fp16, 128 MB ws)
//   5. row softmax in-place fp16 -> fp16 P
//   6. out = P@v         (fp32 out)
// fp16 chosen over bf16: 11-bit mantissa cuts score error ~8x (round 1 failed
// at 0.143 absmax with bf16; budget says fp16 lands ~0.025 vs 0.058 threshold).

typedef _Float16 f16x8 __attribute__((ext_vector_type(8)));
typedef float floatx4 __attribute__((ext_vector_type(4)));

__device__ __forceinline__ unsigned short f2h(float f) {
  __half h = __float2half(f);
  return __builtin_bit_cast(unsigned short, h);
}

// async global->LDS, 16B per lane. LDS dest is wave-uniform base; HW adds lane*16.
__device__ __forceinline__ void async16(const void* g, void* l) {
  __builtin_amdgcn_global_load_lds(
      (__attribute__((address_space(1))) unsigned int*)(g),
      (__attribute__((address_space(3))) unsigned int*)(l),
      16, 0, 0);
}

// ---------------- conversions / transposes ----------------

__global__ __launch_bounds__(256) void conv_f32_f16(const float* __restrict__ in,
                                                    unsigned short* __restrict__ out,
                                                    long n) {
  long i = ((long)blockIdx.x * 256 + threadIdx.x) * 4;
  if (i + 3 < n) {
    float4 f = *(const float4*)(in + i);
    ushort4 o;
    o.x = f2h(f.x); o.y = f2h(f.y); o.z = f2h(f.z); o.w = f2h(f.w);
    *(ushort4*)(out + i) = o;
  }
}

// in[rows][cols] fp32 -> out[cols][rows] fp16
__global__ __launch_bounds__(256) void transpose_f32_f16(const float* __restrict__ in,
                                                         unsigned short* __restrict__ out,
                                                         int rows, int cols) {
  __shared__ float tile[32][33];
  int bx = blockIdx.x * 32;  // col base
  int by = blockIdx.y * 32;  // row base
  int tx = threadIdx.x & 31, ty = threadIdx.x >> 5;  // 32 x 8
  #pragma unroll
  for (int yy = ty; yy < 32; yy += 8)
    tile[yy][tx] = in[(size_t)(by + yy) * cols + bx + tx];
  __syncthreads();
  #pragma unroll
  for (int yy = ty; yy < 32; yy += 8)
    out[(size_t)(bx + yy) * rows + by + tx] = f2h(tile[tx][yy]);
}

// in[rows][cols] u16 -> out[cols][rows] u16 (bit-pattern transpose)
__global__ __launch_bounds__(256) void transpose_u16(const unsigned short* __restrict__ in,
                                                     unsigned short* __restrict__ out,
                                                     int rows, int cols) {
  __shared__ unsigned short tile[32][33];
  int bx = blockIdx.x * 32;
  int by = blockIdx.y * 32;
  int tx = threadIdx.x & 31, ty = threadIdx.x >> 5;
  #pragma unroll
  for (int yy = ty; yy < 32; yy += 8)
    tile[yy][tx] = in[(size_t)(by + yy) * cols + bx + tx];
  __syncthreads();
  #pragma unroll
  for (int yy = ty; yy < 32; yy += 8)
    out[(size_t)(bx + yy) * rows + by + tx] = tile[tx][yy];
}

// ---------------- GEMM: C[M][Nn] = A[M][K] * B[Nn][K]^T (fp16 in, fp32 acc) ----
// m97 recipe: 128x128 block tile, BK=32, 4 waves (2x2), each wave 4x4 mfma 16x16x32.
// MODE 0: +bias, fp16 store.  MODE 1: fp16 store.  MODE 2: fp32 store.
template <int MODE>
__global__ __launch_bounds__(256, 2)
void gemm_bt(const unsigned short* __restrict__ A,
             const unsigned short* __restrict__ B,
             int M, int Nn, int K,
             const float* __restrict__ bias,
             void* __restrict__ out) {
  __shared__ unsigned short As[128 * 32];
  __shared__ unsigned short Bs[128 * 32];
  const int tid  = threadIdx.x;
  const int wave = tid >> 6;
  const int lane = tid & 63;
  const int wm = wave >> 1, wn = wave & 1;
  const int quad = lane >> 4, l16 = lane & 15;
  const long bm = (long)blockIdx.y * 128;
  const long bn = (long)blockIdx.x * 128;

  floatx4 acc[4][4] = {};

  // staging: each wave fills 32 rows of As and Bs; 2 x 16-row (1KB) async ops each.
  const int srow = wave * 32 + (lane >> 2);
  const int scol = (lane & 3) * 8;
  const unsigned short* gA0 = A + (bm + srow) * (long)K + scol;
  const unsigned short* gA1 = gA0 + 16L * K;
  const unsigned short* gB0 = B + (bn + srow) * (long)K + scol;
  const unsigned short* gB1 = gB0 + 16L * K;
  unsigned short* lA0 = &As[(wave * 32) * 32];
  unsigned short* lA1 = &As[(wave * 32 + 16) * 32];
  unsigned short* lB0 = &Bs[(wave * 32) * 32];
  unsigned short* lB1 = &Bs[(wave * 32 + 16) * 32];

  for (int kk = 0; kk < K; kk += 32) {
    async16(gA0 + kk, lA0);
    async16(gA1 + kk, lA1);
    async16(gB0 + kk, lB0);
    async16(gB1 + kk, lB1);
    __syncthreads();  // drains vmcnt -> LDS valid
    f16x8 af[4], bfv[4];
    #pragma unroll
    for (int i = 0; i < 4; ++i) {
      // A frag: row m = l16 (within 16-tile), k = quad*8 + j  (contiguous in LDS)
      af[i]  = *reinterpret_cast<const f16x8*>(&As[(wm * 64 + i * 16 + l16) * 32 + quad * 8]);
      // B frag: col n = l16, k = quad*8 + j
      bfv[i] = *reinterpret_cast<const f16x8*>(&Bs[(wn * 64 + i * 16 + l16) * 32 + quad * 8]);
    }
    #pragma unroll
    for (int i = 0; i < 4; ++i)
      #pragma unroll
      for (int j = 0; j < 4; ++j)
        acc[i][j] = __builtin_amdgcn_mfma_f32_16x16x32_f16(af[i], bfv[j], acc[i][j], 0, 0, 0);
    __syncthreads();  // all waves done reading before next staging
  }

  // epilogue: D[row = quad*4 + r][col = l16] per 16x16 tile (m89/m91-verified layout)
  #pragma unroll
  for (int i = 0; i < 4; ++i) {
    const long row0 = bm + wm * 64 + i * 16 + quad * 4;
    #pragma unroll
    for (int j = 0; j < 4; ++j) {
      const long col = bn + wn * 64 + j * 16 + l16;
      float badd = 0.0f;
      if constexpr (MODE == 0) badd = bias[col];
      #pragma unroll
      for (int r = 0; r < 4; ++r) {
        const float v = acc[i][j][r] + badd;
        const long idx = (row0 + r) * (long)Nn + col;
        if constexpr (MODE == 0) {
          ((unsigned short*)out)[idx] = f2h(v);
        } else if constexpr (MODE == 1) {
          ((unsigned short*)out)[idx] = f2h(v);
        } else {
          ((float*)out)[idx] = v;
        }
      }
    }
  }
}

// ---------------- softmax: one block per row, fp16 -> fp16 in place ----------------
__global__ __launch_bounds__(256) void softmax_rows(unsigned short* __restrict__ S, int n) {
  const int row = blockIdx.x;
  const int tid = threadIdx.x;
  const int lane = tid & 63, w = tid >> 6;
  unsigned short* prow = S + (size_t)row * n;
  const __half* hrow = (const __half*)prow;

  float v[32];
  float m = -1e30f;
  #pragma unroll
  for (int i = 0; i < 32; ++i) {
    v[i] = __half2float(hrow[i * 256 + tid]);
    m = fmaxf(m, v[i]);
  }
  #pragma unroll
  for (int off = 32; off > 0; off >>= 1) m = fmaxf(m, __shfl_down(m, off, 64));
  __shared__ float redm[4];
  if (lane == 0) redm[w] = m;
  __syncthreads();
  m = fmaxf(fmaxf(redm[0], redm[1]), fmaxf(redm[2], redm[3]));

  float s = 0.0f;
  #pragma unroll
  for (int i = 0; i < 32; ++i) {
    v[i] = __expf(v[i] - m);
    s += v[i];
  }
  #pragma unroll
  for (int off = 32; off > 0; off >>= 1) s += __shfl_down(s, off, 64);
  __shared__ float reds[4];
  if (lane == 0) reds[w] = s;
  __syncthreads();
  s = reds[0] + reds[1] + reds[2] + reds[3];
  const float inv = 1.0f / s;

  // each thread overwrites exactly the 2B elements it read -> race-free in place
  #pragma unroll
  for (int i = 0; i < 32; ++i) prow[i * 256 + tid] = f2h(v[i] * inv);
}

// ---------------- launch ----------------
extern "C" void kernel_launch(void* const* d_in, const int* in_sizes, int n_in,
                              void* d_out, int out_size, void* d_ws, size_t ws_size,
                              hipStream_t stream) {
  const int N = 8192, H = 1024;
  const float* x  = (const float*)d_in[0];
  const float* Wq = (const float*)d_in[1];
  const float* bq = (const float*)d_in[2];
  const float* Wk = (const float*)d_in[3];
  const float* bk = (const float*)d_in[4];
  const float* Wv = (const float*)d_in[5];
  const float* bv = (const float*)d_in[6];

  char* p = (char*)d_ws;
  unsigned short* xh  = (unsigned short*)p; p += (size_t)N * H * 2;  // 16 MB
  unsigned short* WqT = (unsigned short*)p; p += (size_t)H * H * 2;  // 2 MB
  unsigned short* WkT = (unsigned short*)p; p += (size_t)H * H * 2;
  unsigned short* WvT = (unsigned short*)p; p += (size_t)H * H * 2;
  unsigned short* qh  = (unsigned short*)p; p += (size_t)N * H * 2;  // 16 MB
  unsigned short* kh  = (unsigned short*)p; p += (size_t)N * H * 2;
  unsigned short* vh  = (unsigned short*)p; p += (size_t)N * H * 2;
  unsigned short* vth = (unsigned short*)p; p += (size_t)N * H * 2;
  unsigned short* S   = (unsigned short*)p; p += (size_t)N * N * 2;  // 128 MB
  if ((size_t)(p - (char*)d_ws) > ws_size) return;  // ws too small: leave output poisoned

  conv_f32_f16<<<(N * H / 4 + 255) / 256, 256, 0, stream>>>(x, xh, (long)N * H);
  transpose_f32_f16<<<dim3(H / 32, H / 32), 256, 0, stream>>>(Wq, WqT, H, H);
  transpose_f32_f16<<<dim3(H / 32, H / 32), 256, 0, stream>>>(Wk, WkT, H, H);
  transpose_f32_f16<<<dim3(H / 32, H / 32), 256, 0, stream>>>(Wv, WvT, H, H);

  // projections: q/k/v[N][H] fp16
  gemm_bt<0><<<dim3(H / 128, N / 128), 256, 0, stream>>>(xh, WqT, N, H, H, bq, qh);
  gemm_bt<0><<<dim3(H / 128, N / 128), 256, 0, stream>>>(xh, WkT, N, H, H, bk, kh);
  gemm_bt<0><<<dim3(H / 128, N / 128), 256, 0, stream>>>(xh, WvT, N, H, H, bv, vh);
  transpose_u16<<<dim3(H / 32, N / 32), 256, 0, stream>>>(vh, vth, N, H);

  // scores: S[N][N] fp16
  gemm_bt<1><<<dim3(N / 128, N / 128), 256, 0, stream>>>(qh, kh, N, N, H, nullptr, S);
  // softmax in place (fp16 -> fp16 P)
  softmax_rows<<<N, 256, 0, stream>>>(S, N);
  // out = P @ v : fp32
  gemm_bt<2><<<dim3(H / 128, N / 128), 256, 0, stream>>>(S, vth, N, H, N, nullptr, d_out);
}

// Round 3
// 601.849 us; speedup vs baseline: 1.0580x; 1.0580x over previous
//
#include <hip/hip_runtime.h>
#include <hip/hip_bf16.h>
#include <hip/hip_fp16.h>

// Self-attention, N=8192 tokens, H=1024, fp32 in/out.
// fp16 MFMA everywhere (mfma_f32_16x16x32_f16, fp32 acc), BT-form GEMMs.
//   1. x -> fp16; Wq/Wk/Wv -> fp16 transposed
//   2. q,k,v = x@W + b      (one batched dispatch, blockIdx.z = which)
//   3. S = q@k^T  fp16      (128 MB ws)
//   4. row softmax in place
//   5. out = P@v  fp32      (128x256 tile, split-K=2, atomicAdd epilogue)
// Round-3 changes: PV was the bottleneck (243 us, 2 blocks/CU, P re-read 8x).
// -> 256-wide N tile (P re-read 4x) + split-K=2 (16 waves/CU) + fused proj.

typedef _Float16 f16x8 __attribute__((ext_vector_type(8)));
typedef float floatx4 __attribute__((ext_vector_type(4)));

__device__ __forceinline__ unsigned short f2h(float f) {
  __half h = __float2half(f);
  return __builtin_bit_cast(unsigned short, h);
}

// async global->LDS, 16B per lane. LDS dest is wave-uniform base; HW adds lane*16.
__device__ __forceinline__ void async16(const void* g, void* l) {
  __builtin_amdgcn_global_load_lds(
      (__attribute__((address_space(1))) unsigned int*)(g),
      (__attribute__((address_space(3))) unsigned int*)(l),
      16, 0, 0);
}

// ---------------- conversions / transposes ----------------

__global__ __launch_bounds__(256) void conv_f32_f16(const float* __restrict__ in,
                                                    unsigned short* __restrict__ out,
                                                    long n) {
  long i = ((long)blockIdx.x * 256 + threadIdx.x) * 4;
  if (i + 3 < n) {
    float4 f = *(const float4*)(in + i);
    ushort4 o;
    o.x = f2h(f.x); o.y = f2h(f.y); o.z = f2h(f.z); o.w = f2h(f.w);
    *(ushort4*)(out + i) = o;
  }
}

// in[rows][cols] fp32 -> out[cols][rows] fp16; z selects one of 3 matrices
__global__ __launch_bounds__(256) void transpose_f32_f16_3(const float* __restrict__ in0,
                                                           const float* __restrict__ in1,
                                                           const float* __restrict__ in2,
                                                           unsigned short* __restrict__ out,
                                                           int rows, int cols) {
  const float* in = (blockIdx.z == 0) ? in0 : (blockIdx.z == 1) ? in1 : in2;
  unsigned short* o = out + (size_t)blockIdx.z * rows * cols;
  __shared__ float tile[32][33];
  int bx = blockIdx.x * 32;
  int by = blockIdx.y * 32;
  int tx = threadIdx.x & 31, ty = threadIdx.x >> 5;
  #pragma unroll
  for (int yy = ty; yy < 32; yy += 8)
    tile[yy][tx] = in[(size_t)(by + yy) * cols + bx + tx];
  __syncthreads();
  #pragma unroll
  for (int yy = ty; yy < 32; yy += 8)
    o[(size_t)(bx + yy) * rows + by + tx] = f2h(tile[tx][yy]);
}

// in[rows][cols] u16 -> out[cols][rows] u16
__global__ __launch_bounds__(256) void transpose_u16(const unsigned short* __restrict__ in,
                                                     unsigned short* __restrict__ out,
                                                     int rows, int cols) {
  __shared__ unsigned short tile[32][33];
  int bx = blockIdx.x * 32;
  int by = blockIdx.y * 32;
  int tx = threadIdx.x & 31, ty = threadIdx.x >> 5;
  #pragma unroll
  for (int yy = ty; yy < 32; yy += 8)
    tile[yy][tx] = in[(size_t)(by + yy) * cols + bx + tx];
  __syncthreads();
  #pragma unroll
  for (int yy = ty; yy < 32; yy += 8)
    out[(size_t)(bx + yy) * rows + by + tx] = tile[tx][yy];
}

// ---- GEMM 128x128 (m97 recipe): C[M][Nn] = A[M][K]*B[Nn][K]^T, fp16 in, f32 acc ----
// MODE 0: batched proj (blockIdx.z selects W/bias/out; +bias, fp16 store)
// MODE 1: plain fp16 store (scores)
template <int MODE>
__global__ __launch_bounds__(256, 4)
void gemm_bt(const unsigned short* __restrict__ A,
             const unsigned short* __restrict__ B,
             int M, int Nn, int K,
             const float* __restrict__ b0, const float* __restrict__ b1,
             const float* __restrict__ b2,
             unsigned short* __restrict__ out) {
  if constexpr (MODE == 0) {
    B   += (size_t)blockIdx.z * Nn * K;
    out += (size_t)blockIdx.z * M * Nn;
  }
  const float* bias = (MODE != 0) ? nullptr
                      : (blockIdx.z == 0) ? b0 : (blockIdx.z == 1) ? b1 : b2;
  __shared__ unsigned short As[128 * 32];
  __shared__ unsigned short Bs[128 * 32];
  const int tid  = threadIdx.x;
  const int wave = tid >> 6;
  const int lane = tid & 63;
  const int wm = wave >> 1, wn = wave & 1;
  const int quad = lane >> 4, l16 = lane & 15;
  const long bm = (long)blockIdx.y * 128;
  const long bn = (long)blockIdx.x * 128;

  floatx4 acc[4][4] = {};

  const int srow = wave * 32 + (lane >> 2);
  const int scol = (lane & 3) * 8;
  const unsigned short* gA0 = A + (bm + srow) * (long)K + scol;
  const unsigned short* gA1 = gA0 + 16L * K;
  const unsigned short* gB0 = B + (bn + srow) * (long)K + scol;
  const unsigned short* gB1 = gB0 + 16L * K;
  unsigned short* lA0 = &As[(wave * 32) * 32];
  unsigned short* lA1 = &As[(wave * 32 + 16) * 32];
  unsigned short* lB0 = &Bs[(wave * 32) * 32];
  unsigned short* lB1 = &Bs[(wave * 32 + 16) * 32];

  for (int kk = 0; kk < K; kk += 32) {
    async16(gA0 + kk, lA0);
    async16(gA1 + kk, lA1);
    async16(gB0 + kk, lB0);
    async16(gB1 + kk, lB1);
    __syncthreads();
    f16x8 af[4], bfv[4];
    #pragma unroll
    for (int i = 0; i < 4; ++i) {
      af[i]  = *reinterpret_cast<const f16x8*>(&As[(wm * 64 + i * 16 + l16) * 32 + quad * 8]);
      bfv[i] = *reinterpret_cast<const f16x8*>(&Bs[(wn * 64 + i * 16 + l16) * 32 + quad * 8]);
    }
    #pragma unroll
    for (int i = 0; i < 4; ++i)
      #pragma unroll
      for (int j = 0; j < 4; ++j)
        acc[i][j] = __builtin_amdgcn_mfma_f32_16x16x32_f16(af[i], bfv[j], acc[i][j], 0, 0, 0);
    __syncthreads();
  }

  // D[row = quad*4 + r][col = l16] per 16x16 tile
  #pragma unroll
  for (int i = 0; i < 4; ++i) {
    const long row0 = bm + wm * 64 + i * 16 + quad * 4;
    #pragma unroll
    for (int j = 0; j < 4; ++j) {
      const long col = bn + wn * 64 + j * 16 + l16;
      float badd = (MODE == 0) ? bias[col] : 0.0f;
      #pragma unroll
      for (int r = 0; r < 4; ++r)
        out[(row0 + r) * (long)Nn + col] = f2h(acc[i][j][r] + badd);
    }
  }
}

// ---- PV GEMM: out[M][Nn](f32,+=) = A[M][K]*B[Nn][K]^T, 128x256 tile, split-K ----
// 512 threads = 8 waves (2 x 4). Each wave: 4x4 grid of 16x16x32 MFMA.
// grid = (Nn/256, M/128, KSPLIT); epilogue atomicAdd (out pre-zeroed).
__global__ __launch_bounds__(512, 4)
void gemm_pv(const unsigned short* __restrict__ A,
             const unsigned short* __restrict__ B,
             int M, int Nn, int K, int kchunk,
             float* __restrict__ out) {
  __shared__ unsigned short As[128 * 32];   //  8 KB
  __shared__ unsigned short Bs[256 * 32];   // 16 KB
  const int tid  = threadIdx.x;
  const int wave = tid >> 6;      // 0..7
  const int lane = tid & 63;
  const int wm = wave >> 2;       // 0..1  (64-row half)
  const int wn = wave & 3;        // 0..3  (64-col quarter)
  const int quad = lane >> 4, l16 = lane & 15;
  const long bm = (long)blockIdx.y * 128;
  const long bn = (long)blockIdx.x * 256;
  const int kbase = blockIdx.z * kchunk;

  floatx4 acc[4][4] = {};

  // staging: wave stages 16 rows of As and 32 rows of Bs per K-step (3 KB)
  const int scol = (lane & 3) * 8;
  const unsigned short* gA  = A + (bm + wave * 16 + (lane >> 2)) * (long)K + scol + kbase;
  const unsigned short* gB0 = B + (bn + wave * 32 + (lane >> 2)) * (long)K + scol + kbase;
  const unsigned short* gB1 = gB0 + 16L * K;
  unsigned short* lA  = &As[(wave * 16) * 32];
  unsigned short* lB0 = &Bs[(wave * 32) * 32];
  unsigned short* lB1 = &Bs[(wave * 32 + 16) * 32];

  for (int kk = 0; kk < kchunk; kk += 32) {
    async16(gA + kk, lA);
    async16(gB0 + kk, lB0);
    async16(gB1 + kk, lB1);
    __syncthreads();
    f16x8 af[4], bfv[4];
    #pragma unroll
    for (int i = 0; i < 4; ++i) {
      af[i]  = *reinterpret_cast<const f16x8*>(&As[(wm * 64 + i * 16 + l16) * 32 + quad * 8]);
      bfv[i] = *reinterpret_cast<const f16x8*>(&Bs[(wn * 64 + i * 16 + l16) * 32 + quad * 8]);
    }
    #pragma unroll
    for (int i = 0; i < 4; ++i)
      #pragma unroll
      for (int j = 0; j < 4; ++j)
        acc[i][j] = __builtin_amdgcn_mfma_f32_16x16x32_f16(af[i], bfv[j], acc[i][j], 0, 0, 0);
    __syncthreads();
  }

  #pragma unroll
  for (int i = 0; i < 4; ++i) {
    const long row0 = bm + wm * 64 + i * 16 + quad * 4;
    #pragma unroll
    for (int j = 0; j < 4; ++j) {
      const long col = bn + wn * 64 + j * 16 + l16;
      #pragma unroll
      for (int r = 0; r < 4; ++r)
        atomicAdd(&out[(row0 + r) * (long)Nn + col], acc[i][j][r]);
    }
  }
}

// ---------------- softmax: one block per row, fp16 -> fp16 in place ----------------
__global__ __launch_bounds__(256) void softmax_rows(unsigned short* __restrict__ S, int n) {
  const int row = blockIdx.x;
  const int tid = threadIdx.x;
  const int lane = tid & 63, w = tid >> 6;
  unsigned short* prow = S + (size_t)row * n;
  const __half* hrow = (const __half*)prow;

  float v[32];
  float m = -1e30f;
  #pragma unroll
  for (int i = 0; i < 32; ++i) {
    v[i] = __half2float(hrow[i * 256 + tid]);
    m = fmaxf(m, v[i]);
  }
  #pragma unroll
  for (int off = 32; off > 0; off >>= 1) m = fmaxf(m, __shfl_down(m, off, 64));
  __shared__ float redm[4];
  if (lane == 0) redm[w] = m;
  __syncthreads();
  m = fmaxf(fmaxf(redm[0], redm[1]), fmaxf(redm[2], redm[3]));

  float s = 0.0f;
  #pragma unroll
  for (int i = 0; i < 32; ++i) {
    v[i] = __expf(v[i] - m);
    s += v[i];
  }
  #pragma unroll
  for (int off = 32; off > 0; off >>= 1) s += __shfl_down(s, off, 64);
  __shared__ float reds[4];
  if (lane == 0) reds[w] = s;
  __syncthreads();
  s = reds[0] + reds[1] + reds[2] + reds[3];
  const float inv = 1.0f / s;

  #pragma unroll
  for (int i = 0; i < 32; ++i) prow[i * 256 + tid] = f2h(v[i] * inv);
}

// ---------------- launch ----------------
extern "C" void kernel_launch(void* const* d_in, const int* in_sizes, int n_in,
                              void* d_out, int out_size, void* d_ws, size_t ws_size,
                              hipStream_t stream) {
  const int N = 8192, H = 1024;
  const float* x  = (const float*)d_in[0];
  const float* Wq = (const float*)d_in[1];
  const float* bq = (const float*)d_in[2];
  const float* Wk = (const float*)d_in[3];
  const float* bk = (const float*)d_in[4];
  const float* Wv = (const float*)d_in[5];
  const float* bv = (const float*)d_in[6];

  char* p = (char*)d_ws;
  unsigned short* xh  = (unsigned short*)p; p += (size_t)N * H * 2;      // 16 MB
  unsigned short* WT  = (unsigned short*)p; p += (size_t)3 * H * H * 2;  // 6 MB (q,k,v contiguous)
  unsigned short* qkv = (unsigned short*)p; p += (size_t)3 * N * H * 2;  // 48 MB (q,k,v contiguous)
  unsigned short* vth = (unsigned short*)p; p += (size_t)N * H * 2;      // 16 MB
  unsigned short* S   = (unsigned short*)p; p += (size_t)N * N * 2;      // 128 MB
  if ((size_t)(p - (char*)d_ws) > ws_size) return;
  unsigned short* qh = qkv;
  unsigned short* kh = qkv + (size_t)N * H;
  unsigned short* vh = qkv + (size_t)2 * N * H;

  conv_f32_f16<<<(N * H / 4 + 255) / 256, 256, 0, stream>>>(x, xh, (long)N * H);
  transpose_f32_f16_3<<<dim3(H / 32, H / 32, 3), 256, 0, stream>>>(Wq, Wk, Wv, WT, H, H);

  // batched projections: qkv[z][N][H] fp16
  gemm_bt<0><<<dim3(H / 128, N / 128, 3), 256, 0, stream>>>(xh, WT, N, H, H, bq, bk, bv, qkv);
  transpose_u16<<<dim3(H / 32, N / 32), 256, 0, stream>>>(vh, vth, N, H);

  // scores: S[N][N] fp16
  gemm_bt<1><<<dim3(N / 128, N / 128), 256, 0, stream>>>(qh, kh, N, N, H,
                                                         nullptr, nullptr, nullptr, S);
  softmax_rows<<<N, 256, 0, stream>>>(S, N);

  // out = P @ v : fp32, 128x256 tile, split-K=2, atomic accumulate
  hipMemsetAsync(d_out, 0, (size_t)N * H * 4, stream);
  gemm_pv<<<dim3(H / 256, N / 128, 2), 512, 0, stream>>>(S, vth, N, H, N, N / 2,
                                                         (float*)d_out);
}

// Round 4
// 591.631 us; speedup vs baseline: 1.0763x; 1.0173x over previous
//
#include <hip/hip_runtime.h>
#include <hip/hip_bf16.h>
#include <hip/hip_fp16.h>

// Self-attention, N=8192 tokens, H=1024, fp32 in/out.
// fp16 MFMA everywhere (mfma_f32_16x16x32_f16, fp32 acc), BT-form GEMMs.
//   1. x -> fp16; Wq/Wk/Wv -> fp16 transposed
//   2. q,k = x@W + b        (one batched dispatch, blockIdx.z = which)
//      v^T = Wv^T @ x^T + bv (same BT GEMM, row-bias -> no separate transpose)
//   3. S = q@k^T  fp16      (128 MB ws)
//   4. row softmax in place
//   5. out = P@v  fp32      (128x256 tile, BK=64 swizzled, split-K=4, atomicAdd)
// Round-4: PV is reg-capped at 2 blocks/CU (120 regs/wave) -> can't raise waves;
// instead halve barrier-drain events (BK=64) and fill both block slots (split4).

typedef _Float16 f16x8 __attribute__((ext_vector_type(8)));
typedef float floatx4 __attribute__((ext_vector_type(4)));

__device__ __forceinline__ unsigned short f2h(float f) {
  __half h = __float2half(f);
  return __builtin_bit_cast(unsigned short, h);
}

// async global->LDS, 16B per lane. LDS dest is wave-uniform base; HW adds lane*16.
__device__ __forceinline__ void async16(const void* g, void* l) {
  __builtin_amdgcn_global_load_lds(
      (__attribute__((address_space(1))) unsigned int*)(g),
      (__attribute__((address_space(3))) unsigned int*)(l),
      16, 0, 0);
}

// ---------------- conversions / transposes ----------------

__global__ __launch_bounds__(256) void conv_f32_f16(const float* __restrict__ in,
                                                    unsigned short* __restrict__ out,
                                                    long n) {
  long i = ((long)blockIdx.x * 256 + threadIdx.x) * 4;
  if (i + 3 < n) {
    float4 f = *(const float4*)(in + i);
    ushort4 o;
    o.x = f2h(f.x); o.y = f2h(f.y); o.z = f2h(f.z); o.w = f2h(f.w);
    *(ushort4*)(out + i) = o;
  }
}

// in[rows][cols] fp32 -> out[cols][rows] fp16; z selects one of 3 matrices
__global__ __launch_bounds__(256) void transpose_f32_f16_3(const float* __restrict__ in0,
                                                           const float* __restrict__ in1,
                                                           const float* __restrict__ in2,
                                                           unsigned short* __restrict__ out,
                                                           int rows, int cols) {
  const float* in = (blockIdx.z == 0) ? in0 : (blockIdx.z == 1) ? in1 : in2;
  unsigned short* o = out + (size_t)blockIdx.z * rows * cols;
  __shared__ float tile[32][33];
  int bx = blockIdx.x * 32;
  int by = blockIdx.y * 32;
  int tx = threadIdx.x & 31, ty = threadIdx.x >> 5;
  #pragma unroll
  for (int yy = ty; yy < 32; yy += 8)
    tile[yy][tx] = in[(size_t)(by + yy) * cols + bx + tx];
  __syncthreads();
  #pragma unroll
  for (int yy = ty; yy < 32; yy += 8)
    o[(size_t)(bx + yy) * rows + by + tx] = f2h(tile[tx][yy]);
}

// ---- GEMM 128x128 (m97 recipe): C[M][Nn] = A[M][K]*B[Nn][K]^T, fp16 in, f32 acc ----
// MODE 0: batched proj (blockIdx.z selects W/bias/out; +bias[col], fp16 store)
// MODE 1: plain fp16 store (scores)
// MODE 2: +bias[row], fp16 store (v^T projection)
template <int MODE>
__global__ __launch_bounds__(256, 4)
void gemm_bt(const unsigned short* __restrict__ A,
             const unsigned short* __restrict__ B,
             int M, int Nn, int K,
             const float* __restrict__ b0, const float* __restrict__ b1,
             unsigned short* __restrict__ out) {
  if constexpr (MODE == 0) {
    B   += (size_t)blockIdx.z * Nn * K;
    out += (size_t)blockIdx.z * M * Nn;
  }
  const float* bias = (MODE == 1) ? nullptr
                      : (MODE == 2) ? b0
                      : (blockIdx.z == 0) ? b0 : b1;
  __shared__ unsigned short As[128 * 32];
  __shared__ unsigned short Bs[128 * 32];
  const int tid  = threadIdx.x;
  const int wave = tid >> 6;
  const int lane = tid & 63;
  const int wm = wave >> 1, wn = wave & 1;
  const int quad = lane >> 4, l16 = lane & 15;
  const long bm = (long)blockIdx.y * 128;
  const long bn = (long)blockIdx.x * 128;

  floatx4 acc[4][4] = {};

  const int srow = wave * 32 + (lane >> 2);
  const int scol = (lane & 3) * 8;
  const unsigned short* gA0 = A + (bm + srow) * (long)K + scol;
  const unsigned short* gA1 = gA0 + 16L * K;
  const unsigned short* gB0 = B + (bn + srow) * (long)K + scol;
  const unsigned short* gB1 = gB0 + 16L * K;
  unsigned short* lA0 = &As[(wave * 32) * 32];
  unsigned short* lA1 = &As[(wave * 32 + 16) * 32];
  unsigned short* lB0 = &Bs[(wave * 32) * 32];
  unsigned short* lB1 = &Bs[(wave * 32 + 16) * 32];

  for (int kk = 0; kk < K; kk += 32) {
    async16(gA0 + kk, lA0);
    async16(gA1 + kk, lA1);
    async16(gB0 + kk, lB0);
    async16(gB1 + kk, lB1);
    __syncthreads();
    f16x8 af[4], bfv[4];
    #pragma unroll
    for (int i = 0; i < 4; ++i) {
      af[i]  = *reinterpret_cast<const f16x8*>(&As[(wm * 64 + i * 16 + l16) * 32 + quad * 8]);
      bfv[i] = *reinterpret_cast<const f16x8*>(&Bs[(wn * 64 + i * 16 + l16) * 32 + quad * 8]);
    }
    #pragma unroll
    for (int i = 0; i < 4; ++i)
      #pragma unroll
      for (int j = 0; j < 4; ++j)
        acc[i][j] = __builtin_amdgcn_mfma_f32_16x16x32_f16(af[i], bfv[j], acc[i][j], 0, 0, 0);
    __syncthreads();
  }

  // D[row = quad*4 + r][col = l16] per 16x16 tile
  #pragma unroll
  for (int i = 0; i < 4; ++i) {
    const long row0 = bm + wm * 64 + i * 16 + quad * 4;
    #pragma unroll
    for (int j = 0; j < 4; ++j) {
      const long col = bn + wn * 64 + j * 16 + l16;
      const float cb = (MODE == 0) ? bias[col] : 0.0f;
      #pragma unroll
      for (int r = 0; r < 4; ++r) {
        float v = acc[i][j][r] + cb;
        if constexpr (MODE == 2) v += bias[row0 + r];
        out[(row0 + r) * (long)Nn + col] = f2h(v);
      }
    }
  }
}

// ---- PV GEMM: out[M][Nn](f32,+=) = A[M][K]*B[Nn][K]^T ----
// 128x256 tile, BK=64, 512 threads = 8 waves (2x4), 4x4 16x16x32 MFMA per wave.
// Staged rows are 128 B; 16-B granules XOR-swizzled by (row&7) so frag
// ds_read_b128 stays at the 8-way bank floor (16-way if unswizzled).
// grid = (Nn/256, M/128, KSPLIT); epilogue atomicAdd (out pre-zeroed).
__global__ __launch_bounds__(512, 4)
void gemm_pv(const unsigned short* __restrict__ A,
             const unsigned short* __restrict__ B,
             int M, int Nn, int K, int kchunk,
             float* __restrict__ out) {
  __shared__ unsigned short As[128 * 64];   // 16 KB
  __shared__ unsigned short Bs[256 * 64];   // 32 KB
  const int tid  = threadIdx.x;
  const int wave = tid >> 6;      // 0..7
  const int wv   = __builtin_amdgcn_readfirstlane(wave);  // force scalar
  const int lane = tid & 63;
  const int wm = wv >> 2;         // 0..1  (64-row half)
  const int wn = wv & 3;          // 0..3  (64-col quarter)
  const int quad = lane >> 4, l16 = lane & 15;
  const long bm = (long)blockIdx.y * 128;
  const long bn = (long)blockIdx.x * 256;
  const long kbase = (long)blockIdx.z * kchunk;

  floatx4 acc[4][4] = {};

  // staging: op = 1 KB = 8 rows x 128 B. A: 16 ops, B: 32 ops.
  // wave w handles A ops {2w,2w+1}, B ops {4w..4w+3}.
  // lane -> (row = lane>>3, granule = (lane&7) ^ (lane>>3))  [XOR swizzle]
  const int rl = lane >> 3;
  const int gc = (lane & 7) ^ rl;
  const unsigned short* gA = A + (bm + rl) * (long)K + gc * 8 + kbase;
  const unsigned short* gB = B + (bn + rl) * (long)K + gc * 8 + kbase;
  const long opA0 = (long)(wv * 2) * 8 * K, opA1 = opA0 + 8L * K;
  const long opB0 = (long)(wv * 4) * 8 * K, opB1 = opB0 + 8L * K;
  const long opB2 = opB1 + 8L * K,          opB3 = opB2 + 8L * K;
  unsigned short* lA = &As[(wv * 2) * 512];
  unsigned short* lB = &Bs[(wv * 4) * 512];

  for (int kk = 0; kk < kchunk; kk += 64) {
    async16(gA + opA0 + kk, lA);
    async16(gA + opA1 + kk, lA + 512);
    async16(gB + opB0 + kk, lB);
    async16(gB + opB1 + kk, lB + 512);
    async16(gB + opB2 + kk, lB + 1024);
    async16(gB + opB3 + kk, lB + 1536);
    __syncthreads();
    #pragma unroll
    for (int ks = 0; ks < 2; ++ks) {
      f16x8 af[4], bfv[4];
      #pragma unroll
      for (int i = 0; i < 4; ++i) {
        const int ga = (ks * 4 + quad) ^ (l16 & 7);  // unswizzle granule
        af[i]  = *reinterpret_cast<const f16x8*>(&As[(wm * 64 + i * 16 + l16) * 64 + ga * 8]);
        bfv[i] = *reinterpret_cast<const f16x8*>(&Bs[(wn * 64 + i * 16 + l16) * 64 + ga * 8]);
      }
      #pragma unroll
      for (int i = 0; i < 4; ++i)
        #pragma unroll
        for (int j = 0; j < 4; ++j)
          acc[i][j] = __builtin_amdgcn_mfma_f32_16x16x32_f16(af[i], bfv[j], acc[i][j], 0, 0, 0);
    }
    __syncthreads();
  }

  #pragma unroll
  for (int i = 0; i < 4; ++i) {
    const long row0 = bm + wm * 64 + i * 16 + quad * 4;
    #pragma unroll
    for (int j = 0; j < 4; ++j) {
      const long col = bn + wn * 64 + j * 16 + l16;
      #pragma unroll
      for (int r = 0; r < 4; ++r)
        atomicAdd(&out[(row0 + r) * (long)Nn + col], acc[i][j][r]);
    }
  }
}

// ---------------- softmax: one block per row, fp16 -> fp16 in place ----------------
__global__ __launch_bounds__(256) void softmax_rows(unsigned short* __restrict__ S, int n) {
  const int row = blockIdx.x;
  const int tid = threadIdx.x;
  const int lane = tid & 63, w = tid >> 6;
  unsigned short* prow = S + (size_t)row * n;
  const __half* hrow = (const __half*)prow;

  float v[32];
  float m = -1e30f;
  #pragma unroll
  for (int i = 0; i < 32; ++i) {
    v[i] = __half2float(hrow[i * 256 + tid]);
    m = fmaxf(m, v[i]);
  }
  #pragma unroll
  for (int off = 32; off > 0; off >>= 1) m = fmaxf(m, __shfl_down(m, off, 64));
  __shared__ float redm[4];
  if (lane == 0) redm[w] = m;
  __syncthreads();
  m = fmaxf(fmaxf(redm[0], redm[1]), fmaxf(redm[2], redm[3]));

  float s = 0.0f;
  #pragma unroll
  for (int i = 0; i < 32; ++i) {
    v[i] = __expf(v[i] - m);
    s += v[i];
  }
  #pragma unroll
  for (int off = 32; off > 0; off >>= 1) s += __shfl_down(s, off, 64);
  __shared__ float reds[4];
  if (lane == 0) reds[w] = s;
  __syncthreads();
  s = reds[0] + reds[1] + reds[2] + reds[3];
  const float inv = 1.0f / s;

  #pragma unroll
  for (int i = 0; i < 32; ++i) prow[i * 256 + tid] = f2h(v[i] * inv);
}

// ---------------- launch ----------------
extern "C" void kernel_launch(void* const* d_in, const int* in_sizes, int n_in,
                              void* d_out, int out_size, void* d_ws, size_t ws_size,
                              hipStream_t stream) {
  const int N = 8192, H = 1024;
  const float* x  = (const float*)d_in[0];
  const float* Wq = (const float*)d_in[1];
  const float* bq = (const float*)d_in[2];
  const float* Wk = (const float*)d_in[3];
  const float* bk = (const float*)d_in[4];
  const float* Wv = (const float*)d_in[5];
  const float* bv = (const float*)d_in[6];

  char* p = (char*)d_ws;
  unsigned short* xh  = (unsigned short*)p; p += (size_t)N * H * 2;      // 16 MB
  unsigned short* WT  = (unsigned short*)p; p += (size_t)3 * H * H * 2;  // 6 MB (WqT,WkT,WvT)
  unsigned short* qk  = (unsigned short*)p; p += (size_t)2 * N * H * 2;  // 32 MB (q,k contiguous)
  unsigned short* vth = (unsigned short*)p; p += (size_t)N * H * 2;      // 16 MB (v^T)
  unsigned short* S   = (unsigned short*)p; p += (size_t)N * N * 2;      // 128 MB
  if ((size_t)(p - (char*)d_ws) > ws_size) return;
  unsigned short* qh  = qk;
  unsigned short* kh  = qk + (size_t)N * H;
  unsigned short* WvT = WT + (size_t)2 * H * H;

  conv_f32_f16<<<(N * H / 4 + 255) / 256, 256, 0, stream>>>(x, xh, (long)N * H);
  transpose_f32_f16_3<<<dim3(H / 32, H / 32, 3), 256, 0, stream>>>(Wq, Wk, Wv, WT, H, H);

  // q,k projections (batched over z): qk[z][N][H] fp16
  gemm_bt<0><<<dim3(H / 128, N / 128, 2), 256, 0, stream>>>(xh, WT, N, H, H, bq, bk, qk);
  // v^T directly: vth[h][n] = sum_k Wv[k][h] x[n][k] + bv[h]  (row-bias)
  gemm_bt<2><<<dim3(N / 128, H / 128), 256, 0, stream>>>(WvT, xh, H, N, H, bv, nullptr, vth);

  // scores: S[N][N] fp16
  gemm_bt<1><<<dim3(N / 128, N / 128), 256, 0, stream>>>(qh, kh, N, N, H,
                                                         nullptr, nullptr, S);
  softmax_rows<<<N, 256, 0, stream>>>(S, N);

  // out = P @ v : fp32, 128x256 tile, BK=64, split-K=4, atomic accumulate
  hipMemsetAsync(d_out, 0, (size_t)N * H * 4, stream);
  gemm_pv<<<dim3(H / 256, N / 128, 4), 512, 0, stream>>>(S, vth, N, H, N, N / 4,
                                                         (float*)d_out);
}